// Round 1
// baseline (976.910 us; speedup 1.0000x reference)
//
#include <hip/hip_runtime.h>
#include <math.h>

#define N_NODES 100000
#define N_EDGES 3200000
#define IN_DIM  128
#define OUT_DIM 64

// ---------------------------------------------------------------------------
// Kernel 1: base = feature @ W_lin ; u1 = tanh(base)
// Thread-per-row. W_lin accessed with wave-uniform addresses -> scalar loads.
// ---------------------------------------------------------------------------
__global__ __launch_bounds__(256) void gemm_base_tanh(
    const float* __restrict__ feature,
    const float* __restrict__ Wlin,
    float* __restrict__ base,
    float* __restrict__ u1)
{
    int row = blockIdx.x * 256 + threadIdx.x;
    if (row >= N_NODES) return;

    const float4* frow = reinterpret_cast<const float4*>(feature + (size_t)row * IN_DIM);
    const float4* Wv   = reinterpret_cast<const float4*>(Wlin);   // [IN_DIM][16] float4

    float4 acc[16];
#pragma unroll
    for (int j = 0; j < 16; ++j) acc[j] = make_float4(0.f, 0.f, 0.f, 0.f);

    for (int k4 = 0; k4 < IN_DIM / 4; ++k4) {
        float4 f = frow[k4];
#pragma unroll
        for (int kk = 0; kk < 4; ++kk) {
            float fk = (kk == 0) ? f.x : (kk == 1) ? f.y : (kk == 2) ? f.z : f.w;
            const float4* wr = Wv + (size_t)(k4 * 4 + kk) * (OUT_DIM / 4);
#pragma unroll
            for (int j = 0; j < 16; ++j) {
                float4 w = wr[j];
                acc[j].x = fmaf(fk, w.x, acc[j].x);
                acc[j].y = fmaf(fk, w.y, acc[j].y);
                acc[j].z = fmaf(fk, w.z, acc[j].z);
                acc[j].w = fmaf(fk, w.w, acc[j].w);
            }
        }
    }

    float4* brow = reinterpret_cast<float4*>(base + (size_t)row * OUT_DIM);
    float4* urow = reinterpret_cast<float4*>(u1   + (size_t)row * OUT_DIM);
#pragma unroll
    for (int j = 0; j < 16; ++j) {
        brow[j] = acc[j];
        float4 t;
        t.x = tanhf(acc[j].x);
        t.y = tanhf(acc[j].y);
        t.z = tanhf(acc[j].z);
        t.w = tanhf(acc[j].w);
        urow[j] = t;
    }
}

// ---------------------------------------------------------------------------
// Kernel 2: m[dst] += u1[src] over all edges. Wave-per-edge, lane = column.
// u1 row read is one coalesced 256B access; m row update is 64 f32 atomics.
// ---------------------------------------------------------------------------
__global__ __launch_bounds__(256) void scatter_sum(
    const int* __restrict__ src,
    const int* __restrict__ dst,
    const float* __restrict__ u1,
    float* __restrict__ m)
{
    int lane = threadIdx.x & 63;
    int wid  = (blockIdx.x * 256 + threadIdx.x) >> 6;
    int nwaves = gridDim.x * 4;

    for (int e = wid; e < N_EDGES; e += nwaves) {
        int s = src[e];   // wave-uniform broadcast load
        int d = dst[e];
        float v = u1[(size_t)s * OUT_DIM + lane];
        atomicAdd(m + (size_t)d * OUT_DIM + lane, v);
    }
}

// ---------------------------------------------------------------------------
// Kernel 3: out = tanh(base + relu(m @ W_d1) @ W_d2)
// Thread-per-row. Layer 1: runtime k-loop (m streamed from global).
// Layer 2: fully unrolled (t lives in registers, static extraction).
// ---------------------------------------------------------------------------
__global__ __launch_bounds__(256) void dense_tanh(
    const float* __restrict__ m,
    const float* __restrict__ W1,
    const float* __restrict__ W2,
    const float* __restrict__ base,
    float* __restrict__ out)
{
    int row = blockIdx.x * 256 + threadIdx.x;
    if (row >= N_NODES) return;

    const float4* mrow = reinterpret_cast<const float4*>(m + (size_t)row * OUT_DIM);
    const float4* W1v  = reinterpret_cast<const float4*>(W1);  // [64][16] float4
    const float4* W2v  = reinterpret_cast<const float4*>(W2);

    // ---- layer 1: t = relu(m @ W1) ----
    float4 t[16];
#pragma unroll
    for (int j = 0; j < 16; ++j) t[j] = make_float4(0.f, 0.f, 0.f, 0.f);

    for (int k4 = 0; k4 < OUT_DIM / 4; ++k4) {
        float4 mv = mrow[k4];
#pragma unroll
        for (int kk = 0; kk < 4; ++kk) {
            float mk = (kk == 0) ? mv.x : (kk == 1) ? mv.y : (kk == 2) ? mv.z : mv.w;
            const float4* wr = W1v + (size_t)(k4 * 4 + kk) * 16;
#pragma unroll
            for (int j = 0; j < 16; ++j) {
                float4 w = wr[j];
                t[j].x = fmaf(mk, w.x, t[j].x);
                t[j].y = fmaf(mk, w.y, t[j].y);
                t[j].z = fmaf(mk, w.z, t[j].z);
                t[j].w = fmaf(mk, w.w, t[j].w);
            }
        }
    }
#pragma unroll
    for (int j = 0; j < 16; ++j) {
        t[j].x = fmaxf(t[j].x, 0.f);
        t[j].y = fmaxf(t[j].y, 0.f);
        t[j].z = fmaxf(t[j].z, 0.f);
        t[j].w = fmaxf(t[j].w, 0.f);
    }

    // ---- layer 2: h = t @ W2 (full static unroll so t stays in registers) ----
    float4 h[16];
#pragma unroll
    for (int j = 0; j < 16; ++j) h[j] = make_float4(0.f, 0.f, 0.f, 0.f);

#pragma unroll
    for (int k = 0; k < OUT_DIM; ++k) {
        float4 tv = t[k / 4];
        float tk = ((k & 3) == 0) ? tv.x : ((k & 3) == 1) ? tv.y : ((k & 3) == 2) ? tv.z : tv.w;
        const float4* wr = W2v + (size_t)k * 16;
#pragma unroll
        for (int j = 0; j < 16; ++j) {
            float4 w = wr[j];
            h[j].x = fmaf(tk, w.x, h[j].x);
            h[j].y = fmaf(tk, w.y, h[j].y);
            h[j].z = fmaf(tk, w.z, h[j].z);
            h[j].w = fmaf(tk, w.w, h[j].w);
        }
    }

    const float4* brow = reinterpret_cast<const float4*>(base + (size_t)row * OUT_DIM);
    float4* orow = reinterpret_cast<float4*>(out + (size_t)row * OUT_DIM);
#pragma unroll
    for (int j = 0; j < 16; ++j) {
        float4 b = brow[j];
        float4 o;
        o.x = tanhf(b.x + h[j].x);
        o.y = tanhf(b.y + h[j].y);
        o.z = tanhf(b.z + h[j].z);
        o.w = tanhf(b.w + h[j].w);
        orow[j] = o;
    }
}

// ---------------------------------------------------------------------------
extern "C" void kernel_launch(void* const* d_in, const int* in_sizes, int n_in,
                              void* d_out, int out_size, void* d_ws, size_t ws_size,
                              hipStream_t stream)
{
    const float* feature = (const float*)d_in[0];
    const int*   src     = (const int*)d_in[1];
    const int*   dst     = (const int*)d_in[2];
    const float* W_lin   = (const float*)d_in[3];
    const float* W_d1    = (const float*)d_in[4];
    const float* W_d2    = (const float*)d_in[5];
    float* out = (float*)d_out;

    const size_t NODE_F = (size_t)N_NODES * OUT_DIM;   // 6.4M floats
    float* base = (float*)d_ws;
    float* u1   = base + NODE_F;
    float* m    = u1 + NODE_F;

    // iter 1 collapses: u1 = tanh(feature @ W_lin), since u0 == 0 -> h == 0.
    hipMemsetAsync(m, 0, NODE_F * sizeof(float), stream);

    int row_blocks = (N_NODES + 255) / 256;
    gemm_base_tanh<<<row_blocks, 256, 0, stream>>>(feature, W_lin, base, u1);
    scatter_sum<<<2048, 256, 0, stream>>>(src, dst, u1, m);
    dense_tanh<<<row_blocks, 256, 0, stream>>>(m, W_d1, W_d2, base, out);
}